// Round 1
// baseline (14850.771 us; speedup 1.0000x reference)
//
#include <hip/hip_runtime.h>
#include <math.h>

#define NA 10
#define NT 65
#define NB 128
#define XDIM 2
#define YDIM 20
#define ZDIM 64
#define HDIM 256
#define MDIM 90
#define RMDIM 256
#define NSTEP (NT - 1)
#define LOG2PI 1.8378770664093453f

// weight strides
#define ENC_W1_S (348 * 256)
#define PRI_W1_S (346 * 256)
#define DEC_W1_S (430 * 256)
#define GRU_WIH_S (66 * 768)
#define GRU_WHH_S (256 * 768)
#define W2_S (256 * 256)
#define HEADW_S (256 * 64)

static __device__ __forceinline__ float sp(float x) {
    // softplus, matches jax.nn.softplus: max(x,0)+log1p(exp(-|x|))
    return fmaxf(x, 0.f) + log1pf(expf(-fabsf(x)));
}
static __device__ __forceinline__ float sigm(float x) { return 1.f / (1.f + expf(-x)); }
static __device__ __forceinline__ float relu(float x) { return fmaxf(x, 0.f); }

struct Seg {
    const float* x;  // X base: row m at x + m*xld, k contiguous
    int xld;
    const float* w;  // W base (already offset to col tile): w + k*wld + cc
    int wld;
    int nk;
};

// 64x64 output tile GEMM core. 256 threads: rg=tid&15 (4 rows each), cg=tid>>4 (4 cols each).
__device__ __forceinline__ void gemm_tile(float acc[4][4], const Seg* segs, int nseg, int tid,
                                          float Xs[64][65], float Ws[64][64]) {
    const int lk = tid & 63;
    const int wv = tid >> 6;
    const int rg = tid & 15, cg = tid >> 4;
    for (int s = 0; s < nseg; ++s) {
        const float* __restrict__ xp = segs[s].x;
        const float* __restrict__ wp = segs[s].w;
        const int xld = segs[s].xld, wld = segs[s].wld, nk = segs[s].nk;
        for (int kb = 0; kb < nk; kb += 64) {
            const int kx = kb + lk;
            const bool okx = kx < nk;
#pragma unroll
            for (int m = wv; m < 64; m += 4) {
                Xs[m][lk] = okx ? xp[m * xld + kx] : 0.f;
            }
#pragma unroll
            for (int kk = wv; kk < 64; kk += 4) {
                int k = kb + kk;
                Ws[kk][lk] = (k < nk) ? wp[k * wld + lk] : 0.f;
            }
            __syncthreads();
#pragma unroll 8
            for (int kk = 0; kk < 64; ++kk) {
                const float4 w4 = *(const float4*)&Ws[kk][cg * 4];
                const float x0 = Xs[rg * 4 + 0][kk];
                const float x1 = Xs[rg * 4 + 1][kk];
                const float x2 = Xs[rg * 4 + 2][kk];
                const float x3 = Xs[rg * 4 + 3][kk];
                acc[0][0] = fmaf(x0, w4.x, acc[0][0]);
                acc[0][1] = fmaf(x0, w4.y, acc[0][1]);
                acc[0][2] = fmaf(x0, w4.z, acc[0][2]);
                acc[0][3] = fmaf(x0, w4.w, acc[0][3]);
                acc[1][0] = fmaf(x1, w4.x, acc[1][0]);
                acc[1][1] = fmaf(x1, w4.y, acc[1][1]);
                acc[1][2] = fmaf(x1, w4.z, acc[1][2]);
                acc[1][3] = fmaf(x1, w4.w, acc[1][3]);
                acc[2][0] = fmaf(x2, w4.x, acc[2][0]);
                acc[2][1] = fmaf(x2, w4.y, acc[2][1]);
                acc[2][2] = fmaf(x2, w4.z, acc[2][2]);
                acc[2][3] = fmaf(x2, w4.w, acc[2][3]);
                acc[3][0] = fmaf(x3, w4.x, acc[3][0]);
                acc[3][1] = fmaf(x3, w4.y, acc[3][1]);
                acc[3][2] = fmaf(x3, w4.z, acc[3][2]);
                acc[3][3] = fmaf(x3, w4.w, acc[3][3]);
            }
            __syncthreads();
        }
    }
}

// dec-head + recon epilogue for a completed step (reads dech2 of that step).
// targ = (step index)+1, i.e. x_t = data[targ]. One wave per (a,b).
__device__ __forceinline__ void dec_epilogue(int ebid, int tid, int targ,
                                             const float* __restrict__ dech2,
                                             const float* __restrict__ decm_W,
                                             const float* __restrict__ decm_b,
                                             const float* __restrict__ decs_W,
                                             const float* __restrict__ decs_b,
                                             const float* __restrict__ data,
                                             double* __restrict__ accd) {
    int widx = ebid * 4 + (tid >> 6);  // 0..1279
    int a = widx >> 7, b = widx & 127;
    int lane = tid & 63;
    const float4 hv = *(const float4*)&dech2[(a * NB + b) * HDIM + lane * 4];
    const float* wmb = decm_W + a * (HDIM * XDIM) + lane * 8;
    const float4 wm0 = *(const float4*)&wmb[0];
    const float4 wm1 = *(const float4*)&wmb[4];
    const float* wsb = decs_W + a * (HDIM * XDIM) + lane * 8;
    const float4 ws0 = *(const float4*)&wsb[0];
    const float4 ws1 = *(const float4*)&wsb[4];
    float m0 = hv.x * wm0.x + hv.y * wm0.z + hv.z * wm1.x + hv.w * wm1.z;
    float m1 = hv.x * wm0.y + hv.y * wm0.w + hv.z * wm1.y + hv.w * wm1.w;
    float s0 = hv.x * ws0.x + hv.y * ws0.z + hv.z * ws1.x + hv.w * ws1.z;
    float s1 = hv.x * ws0.y + hv.y * ws0.w + hv.z * ws1.y + hv.w * ws1.w;
#pragma unroll
    for (int off = 32; off > 0; off >>= 1) {
        m0 += __shfl_down(m0, off, 64);
        m1 += __shfl_down(m1, off, 64);
        s0 += __shfl_down(s0, off, 64);
        s1 += __shfl_down(s1, off, 64);
    }
    if (lane == 0) {
        float dm0 = m0 + decm_b[a * 2 + 0];
        float dm1 = m1 + decm_b[a * 2 + 1];
        float ds0 = sp(s0 + decs_b[a * 2 + 0]);
        float ds1 = sp(s1 + decs_b[a * 2 + 1]);
        float x0 = data[targ * (NB * YDIM) + b * YDIM + a * XDIM + 0];
        float x1 = data[targ * (NB * YDIM) + b * YDIM + a * XDIM + 1];
        float r0 = (x0 - dm0) / ds0, r1 = (x1 - dm1) / ds1;
        float t = 0.5f * r0 * r0 + logf(ds0) + 0.5f * LOG2PI + 0.5f * r1 * r1 + logf(ds1) +
                  0.5f * LOG2PI;
        atomicAdd(&accd[0], (double)t);
    }
}

__global__ __launch_bounds__(256) void k_init(float* __restrict__ h, double* __restrict__ accd) {
    int i = blockIdx.x * 256 + threadIdx.x;
    ((float4*)h)[i] = make_float4(0.f, 0.f, 0.f, 0.f);  // grid sized exactly A*B*RM/4
    if (i == 0) {
        accd[0] = 0.0;
        accd[1] = 0.0;
    }
}

// K1: enc layer1 + pri layer1 (K=256 over h, one-hot/x folded into epilogue). grid 160.
__global__ __launch_bounds__(256) void k1(const float* __restrict__ h,
                                          const float* __restrict__ enc_W1,
                                          const float* __restrict__ enc_b1,
                                          const float* __restrict__ pri_W1,
                                          const float* __restrict__ pri_b1,
                                          const float* __restrict__ data,
                                          const int* __restrict__ macro,
                                          float* __restrict__ ench1, float* __restrict__ prih1,
                                          int t) {
    __shared__ float Xs[64][65];
    __shared__ float Ws[64][64];
    int tid = threadIdx.x, bid = blockIdx.x;
    int a = bid >> 4;
    int r = bid & 15;
    int b0 = (r >> 3) * 64;
    int ct = r & 7;
    bool isenc = ct < 4;
    int c0 = (isenc ? ct : ct - 4) * 64;
    const float* wbase = isenc ? (enc_W1 + a * ENC_W1_S) : (pri_W1 + a * PRI_W1_S);
    int hrow = isenc ? 92 : 90;
    float acc[4][4] = {};
    Seg sg = {h + (a * NB + b0) * RMDIM, RMDIM, wbase + hrow * 256 + c0, 256, 256};
    gemm_tile(acc, &sg, 1, tid, Xs, Ws);
    int rg = tid & 15, cg = tid >> 4;
    int c = c0 + cg * 4;
    const float4 bb = *(const float4*)&((isenc ? enc_b1 : pri_b1)[a * HDIM + c]);
    float4 w0 = make_float4(0, 0, 0, 0), w1 = make_float4(0, 0, 0, 0);
    if (isenc) {
        w0 = *(const float4*)&wbase[0 * 256 + c];
        w1 = *(const float4*)&wbase[1 * 256 + c];
    }
    float* outp = isenc ? ench1 : prih1;
#pragma unroll
    for (int i = 0; i < 4; ++i) {
        int b = b0 + rg * 4 + i;
        int mi = macro[(t * NB + b) * NA + a];
        const float4 mv = *(const float4*)&wbase[((isenc ? 2 + mi : mi)) * 256 + c];
        float a0 = mv.x + bb.x, a1 = mv.y + bb.y, a2 = mv.z + bb.z, a3 = mv.w + bb.w;
        if (isenc) {
            float xv0 = data[(t + 1) * (NB * YDIM) + b * YDIM + a * XDIM + 0];
            float xv1 = data[(t + 1) * (NB * YDIM) + b * YDIM + a * XDIM + 1];
            a0 += xv0 * w0.x + xv1 * w1.x;
            a1 += xv0 * w0.y + xv1 * w1.y;
            a2 += xv0 * w0.z + xv1 * w1.z;
            a3 += xv0 * w0.w + xv1 * w1.w;
        }
        float4 o;
        o.x = relu(acc[i][0] + a0);
        o.y = relu(acc[i][1] + a1);
        o.z = relu(acc[i][2] + a2);
        o.w = relu(acc[i][3] + a3);
        *(float4*)&outp[(a * NB + b) * HDIM + c] = o;
    }
}

// K2: enc/pri layer2 (grid blocks 0..159) + dec-head/recon epilogue of previous step
// (blocks 160..479, active when t>0).
__global__ __launch_bounds__(256) void k2(const float* __restrict__ ench1,
                                          const float* __restrict__ prih1,
                                          const float* __restrict__ enc_W2,
                                          const float* __restrict__ enc_b2,
                                          const float* __restrict__ pri_W2,
                                          const float* __restrict__ pri_b2,
                                          float* __restrict__ ench2, float* __restrict__ prih2,
                                          const float* __restrict__ dech2,
                                          const float* __restrict__ decm_W,
                                          const float* __restrict__ decm_b,
                                          const float* __restrict__ decs_W,
                                          const float* __restrict__ decs_b,
                                          const float* __restrict__ data,
                                          double* __restrict__ accd, int t) {
    __shared__ float Xs[64][65];
    __shared__ float Ws[64][64];
    int tid = threadIdx.x, bid = blockIdx.x;
    if (bid >= 160) {
        if (t > 0) dec_epilogue(bid - 160, tid, t, dech2, decm_W, decm_b, decs_W, decs_b, data, accd);
        return;
    }
    int a = bid >> 4;
    int r = bid & 15;
    int b0 = (r >> 3) * 64;
    int ct = r & 7;
    bool isenc = ct < 4;
    int c0 = (isenc ? ct : ct - 4) * 64;
    const float* X = (isenc ? ench1 : prih1) + (a * NB + b0) * HDIM;
    const float* W = (isenc ? enc_W2 : pri_W2) + a * W2_S + c0;
    float acc[4][4] = {};
    Seg sg = {X, HDIM, W, HDIM, HDIM};
    gemm_tile(acc, &sg, 1, tid, Xs, Ws);
    int rg = tid & 15, cg = tid >> 4;
    int c = c0 + cg * 4;
    const float4 bb = *(const float4*)&((isenc ? enc_b2 : pri_b2)[a * HDIM + c]);
    float* outp = isenc ? ench2 : prih2;
#pragma unroll
    for (int i = 0; i < 4; ++i) {
        int b = b0 + rg * 4 + i;
        float4 o;
        o.x = relu(acc[i][0] + bb.x);
        o.y = relu(acc[i][1] + bb.y);
        o.z = relu(acc[i][2] + bb.z);
        o.w = relu(acc[i][3] + bb.w);
        *(float4*)&outp[(a * NB + b) * HDIM + c] = o;
    }
}

// K3: the four z-heads as GEMMs (no activation). grid 80: (a, mtile, head).
__global__ __launch_bounds__(256) void k3(const float* __restrict__ ench2,
                                          const float* __restrict__ prih2,
                                          const float* __restrict__ encm_W,
                                          const float* __restrict__ encm_b,
                                          const float* __restrict__ encs_W,
                                          const float* __restrict__ encs_b,
                                          const float* __restrict__ prim_W,
                                          const float* __restrict__ prim_b,
                                          const float* __restrict__ pris_W,
                                          const float* __restrict__ pris_b,
                                          float* __restrict__ heads) {
    __shared__ float Xs[64][65];
    __shared__ float Ws[64][64];
    int tid = threadIdx.x, bid = blockIdx.x;
    int a = bid >> 3;
    int r = bid & 7;
    int b0 = (r >> 2) * 64;
    int ct = r & 3;
    const float* X = (ct < 2 ? ench2 : prih2) + (a * NB + b0) * HDIM;
    const float* Wt;
    const float* Bt;
    if (ct == 0) { Wt = encm_W; Bt = encm_b; }
    else if (ct == 1) { Wt = encs_W; Bt = encs_b; }
    else if (ct == 2) { Wt = prim_W; Bt = prim_b; }
    else { Wt = pris_W; Bt = pris_b; }
    float acc[4][4] = {};
    Seg sg = {X, HDIM, Wt + a * HEADW_S, ZDIM, HDIM};
    gemm_tile(acc, &sg, 1, tid, Xs, Ws);
    int rg = tid & 15, cg = tid >> 4;
    int c = cg * 4;
    const float4 bb = *(const float4*)&Bt[a * ZDIM + c];
#pragma unroll
    for (int i = 0; i < 4; ++i) {
        int b = b0 + rg * 4 + i;
        float4 o;
        o.x = acc[i][0] + bb.x;
        o.y = acc[i][1] + bb.y;
        o.z = acc[i][2] + bb.z;
        o.w = acc[i][3] + bb.w;
        *(float4*)&heads[(a * NB + b) * 256 + ct * 64 + c] = o;
    }
}

// K3b: z = em + eps*es; kl accumulation. grid 320x256 = 81920 = A*B*ZD.
__global__ __launch_bounds__(256) void k3b(const float* __restrict__ heads,
                                           const float* __restrict__ eps,
                                           float* __restrict__ Z, double* __restrict__ accd,
                                           int t) {
    int tid = threadIdx.x;
    int i = blockIdx.x * 256 + tid;
    int a = i >> 13;
    int rb = i & 8191;
    int b = rb >> 6, zd = rb & 63;
    const float* hh = heads + (a * NB + b) * 256;
    float em = hh[zd];
    float es = sp(hh[64 + zd]);
    float pm = hh[128 + zd];
    float ps = sp(hh[192 + zd]);
    float e = eps[((t * NA + a) * NB + b) * ZDIM + zd];
    Z[(a * NB + b) * ZDIM + zd] = em + e * es;
    float dm = em - pm;
    float kt = 0.5f * (2.f * logf(ps) - 2.f * logf(es) + (es * es + dm * dm) / (ps * ps) - 1.f);
    __shared__ float red[256];
    red[tid] = kt;
    __syncthreads();
#pragma unroll
    for (int s = 128; s > 0; s >>= 1) {
        if (tid < s) red[tid] += red[tid + s];
        __syncthreads();
    }
    if (tid == 0) atomicAdd(&accd[1], (double)red[0]);
}

// K4: dec layer1 (blocks 0..79), gru gi (80..319), gru gh (320..559).
__global__ __launch_bounds__(256) void k4(const float* __restrict__ h, const float* __restrict__ Z,
                                          const float* __restrict__ data,
                                          const int* __restrict__ macro,
                                          const float* __restrict__ dec_W1,
                                          const float* __restrict__ dec_b1,
                                          const float* __restrict__ gru_Wih,
                                          const float* __restrict__ gru_bih,
                                          const float* __restrict__ gru_Whh,
                                          const float* __restrict__ gru_bhh,
                                          float* __restrict__ dech1, float* __restrict__ giB,
                                          float* __restrict__ ghB, int t) {
    __shared__ float Xs[64][65];
    __shared__ float Ws[64][64];
    int tid = threadIdx.x, bid = blockIdx.x;
    int rg = tid & 15, cg = tid >> 4;
    float acc[4][4] = {};
    if (bid < 80) {
        int a = bid >> 3;
        int r = bid & 7;
        int b0 = (r >> 2) * 64;
        int c0 = (r & 3) * 64;
        const float* wbase = dec_W1 + a * DEC_W1_S;
        Seg sg[3] = {
            {data + t * (NB * YDIM) + b0 * YDIM, YDIM, wbase + 0 * 256 + c0, 256, YDIM},
            {Z + (a * NB + b0) * ZDIM, ZDIM, wbase + 110 * 256 + c0, 256, ZDIM},
            {h + (a * NB + b0) * RMDIM, RMDIM, wbase + 174 * 256 + c0, 256, RMDIM}};
        gemm_tile(acc, sg, 3, tid, Xs, Ws);
        int c = c0 + cg * 4;
        const float4 bb = *(const float4*)&dec_b1[a * HDIM + c];
#pragma unroll
        for (int i = 0; i < 4; ++i) {
            int b = b0 + rg * 4 + i;
            int mi = macro[(t * NB + b) * NA + a];
            const float4 mv = *(const float4*)&wbase[(20 + mi) * 256 + c];
            float4 o;
            o.x = relu(acc[i][0] + mv.x + bb.x);
            o.y = relu(acc[i][1] + mv.y + bb.y);
            o.z = relu(acc[i][2] + mv.z + bb.z);
            o.w = relu(acc[i][3] + mv.w + bb.w);
            *(float4*)&dech1[(a * NB + b) * HDIM + c] = o;
        }
    } else if (bid < 320) {
        int j = bid - 80;
        int a = j / 24;
        int r = j % 24;
        int b0 = (r / 12) * 64;
        int c0 = (r % 12) * 64;
        const float* wbase = gru_Wih + a * GRU_WIH_S;
        Seg sg = {Z + (a * NB + b0) * ZDIM, ZDIM, wbase + 2 * 768 + c0, 768, ZDIM};
        gemm_tile(acc, &sg, 1, tid, Xs, Ws);
        int c = c0 + cg * 4;
        const float4 bb = *(const float4*)&gru_bih[a * 768 + c];
        const float4 w0 = *(const float4*)&wbase[0 * 768 + c];
        const float4 w1 = *(const float4*)&wbase[1 * 768 + c];
#pragma unroll
        for (int i = 0; i < 4; ++i) {
            int b = b0 + rg * 4 + i;
            float xv0 = data[(t + 1) * (NB * YDIM) + b * YDIM + a * XDIM + 0];
            float xv1 = data[(t + 1) * (NB * YDIM) + b * YDIM + a * XDIM + 1];
            float4 o;
            o.x = acc[i][0] + xv0 * w0.x + xv1 * w1.x + bb.x;
            o.y = acc[i][1] + xv0 * w0.y + xv1 * w1.y + bb.y;
            o.z = acc[i][2] + xv0 * w0.z + xv1 * w1.z + bb.z;
            o.w = acc[i][3] + xv0 * w0.w + xv1 * w1.w + bb.w;
            *(float4*)&giB[(a * NB + b) * 768 + c] = o;
        }
    } else {
        int j = bid - 320;
        int a = j / 24;
        int r = j % 24;
        int b0 = (r / 12) * 64;
        int c0 = (r % 12) * 64;
        Seg sg = {h + (a * NB + b0) * RMDIM, RMDIM, gru_Whh + a * GRU_WHH_S + c0, 768, RMDIM};
        gemm_tile(acc, &sg, 1, tid, Xs, Ws);
        int c = c0 + cg * 4;
        const float4 bb = *(const float4*)&gru_bhh[a * 768 + c];
#pragma unroll
        for (int i = 0; i < 4; ++i) {
            int b = b0 + rg * 4 + i;
            float4 o;
            o.x = acc[i][0] + bb.x;
            o.y = acc[i][1] + bb.y;
            o.z = acc[i][2] + bb.z;
            o.w = acc[i][3] + bb.w;
            *(float4*)&ghB[(a * NB + b) * 768 + c] = o;
        }
    }
}

// K5: dec layer2 (blocks 0..79) + GRU combine h update in-place (blocks 80..399).
__global__ __launch_bounds__(256) void k5(const float* __restrict__ dech1,
                                          const float* __restrict__ dec_W2,
                                          const float* __restrict__ dec_b2,
                                          float* __restrict__ dech2,
                                          const float* __restrict__ giB,
                                          const float* __restrict__ ghB, float* __restrict__ h) {
    __shared__ float Xs[64][65];
    __shared__ float Ws[64][64];
    int tid = threadIdx.x, bid = blockIdx.x;
    if (bid < 80) {
        int a = bid >> 3;
        int r = bid & 7;
        int b0 = (r >> 2) * 64;
        int c0 = (r & 3) * 64;
        float acc[4][4] = {};
        Seg sg = {dech1 + (a * NB + b0) * HDIM, HDIM, dec_W2 + a * W2_S + c0, HDIM, HDIM};
        gemm_tile(acc, &sg, 1, tid, Xs, Ws);
        int rg = tid & 15, cg = tid >> 4;
        int c = c0 + cg * 4;
        const float4 bb = *(const float4*)&dec_b2[a * HDIM + c];
#pragma unroll
        for (int i = 0; i < 4; ++i) {
            int b = b0 + rg * 4 + i;
            float4 o;
            o.x = relu(acc[i][0] + bb.x);
            o.y = relu(acc[i][1] + bb.y);
            o.z = relu(acc[i][2] + bb.z);
            o.w = relu(acc[i][3] + bb.w);
            *(float4*)&dech2[(a * NB + b) * HDIM + c] = o;
        }
    } else {
        int idx = (bid - 80) * 256 + tid;  // 0..81919, one float4 each over A*B*256
        int rb = idx >> 6;
        int o = (idx & 63) * 4;
        const float4 ir = *(const float4*)&giB[rb * 768 + o];
        const float4 iz = *(const float4*)&giB[rb * 768 + 256 + o];
        const float4 in4 = *(const float4*)&giB[rb * 768 + 512 + o];
        const float4 hr = *(const float4*)&ghB[rb * 768 + o];
        const float4 hz = *(const float4*)&ghB[rb * 768 + 256 + o];
        const float4 hn = *(const float4*)&ghB[rb * 768 + 512 + o];
        float4 hc = *(float4*)&h[rb * 256 + o];
        float r0 = sigm(ir.x + hr.x), r1 = sigm(ir.y + hr.y), r2 = sigm(ir.z + hr.z),
              r3 = sigm(ir.w + hr.w);
        float u0 = sigm(iz.x + hz.x), u1 = sigm(iz.y + hz.y), u2 = sigm(iz.z + hz.z),
              u3 = sigm(iz.w + hz.w);
        float n0 = tanhf(in4.x + r0 * hn.x), n1 = tanhf(in4.y + r1 * hn.y),
              n2 = tanhf(in4.z + r2 * hn.z), n3 = tanhf(in4.w + r3 * hn.w);
        hc.x = (1.f - u0) * n0 + u0 * hc.x;
        hc.y = (1.f - u1) * n1 + u1 * hc.y;
        hc.z = (1.f - u2) * n2 + u2 * hc.z;
        hc.w = (1.f - u3) * n3 + u3 * hc.w;
        *(float4*)&h[rb * 256 + o] = hc;
    }
}

__global__ __launch_bounds__(256) void k_epi_last(const float* __restrict__ dech2,
                                                  const float* __restrict__ decm_W,
                                                  const float* __restrict__ decm_b,
                                                  const float* __restrict__ decs_W,
                                                  const float* __restrict__ decs_b,
                                                  const float* __restrict__ data,
                                                  double* __restrict__ accd, int targ) {
    dec_epilogue(blockIdx.x, threadIdx.x, targ, dech2, decm_W, decm_b, decs_W, decs_b, data, accd);
}

__global__ void k_final(const double* __restrict__ accd, float* __restrict__ out) {
    if (threadIdx.x == 0) {
        out[0] = (float)accd[0];  // recon
        out[1] = (float)accd[1];  // kl
    }
}

extern "C" void kernel_launch(void* const* d_in, const int* in_sizes, int n_in, void* d_out,
                              int out_size, void* d_ws, size_t ws_size, hipStream_t stream) {
    const float* data = (const float*)d_in[0];
    const int* macro = (const int*)d_in[1];
    const float* eps = (const float*)d_in[2];
    const float* enc_W1 = (const float*)d_in[3];
    const float* enc_b1 = (const float*)d_in[4];
    const float* enc_W2 = (const float*)d_in[5];
    const float* enc_b2 = (const float*)d_in[6];
    const float* encm_W = (const float*)d_in[7];
    const float* encm_b = (const float*)d_in[8];
    const float* encs_W = (const float*)d_in[9];
    const float* encs_b = (const float*)d_in[10];
    const float* pri_W1 = (const float*)d_in[11];
    const float* pri_b1 = (const float*)d_in[12];
    const float* pri_W2 = (const float*)d_in[13];
    const float* pri_b2 = (const float*)d_in[14];
    const float* prim_W = (const float*)d_in[15];
    const float* prim_b = (const float*)d_in[16];
    const float* pris_W = (const float*)d_in[17];
    const float* pris_b = (const float*)d_in[18];
    const float* dec_W1 = (const float*)d_in[19];
    const float* dec_b1 = (const float*)d_in[20];
    const float* dec_W2 = (const float*)d_in[21];
    const float* dec_b2 = (const float*)d_in[22];
    const float* decm_W = (const float*)d_in[23];
    const float* decm_b = (const float*)d_in[24];
    const float* decs_W = (const float*)d_in[25];
    const float* decs_b = (const float*)d_in[26];
    const float* gru_Wih = (const float*)d_in[27];
    const float* gru_bih = (const float*)d_in[28];
    const float* gru_Whh = (const float*)d_in[29];
    const float* gru_bhh = (const float*)d_in[30];

    // workspace layout
    double* accd = (double*)d_ws;
    float* base = (float*)((char*)d_ws + 256);
    const int SZH = NA * NB * 256;  // 327680
    float* h = base;
    float* ench1 = h + SZH;
    float* prih1 = ench1 + SZH;
    float* ench2 = prih1 + SZH;
    float* prih2 = ench2 + SZH;
    float* heads = prih2 + SZH;
    float* Z = heads + SZH;                // A*B*64
    float* dech1 = Z + NA * NB * ZDIM;
    float* dech2 = dech1 + SZH;
    float* giB = dech2 + SZH;              // A*B*768
    float* ghB = giB + NA * NB * 768;

    float* out = (float*)d_out;

    k_init<<<320, 256, 0, stream>>>(h, accd);
    for (int t = 0; t < NSTEP; ++t) {
        k1<<<160, 256, 0, stream>>>(h, enc_W1, enc_b1, pri_W1, pri_b1, data, macro, ench1, prih1,
                                    t);
        k2<<<480, 256, 0, stream>>>(ench1, prih1, enc_W2, enc_b2, pri_W2, pri_b2, ench2, prih2,
                                    dech2, decm_W, decm_b, decs_W, decs_b, data, accd, t);
        k3<<<80, 256, 0, stream>>>(ench2, prih2, encm_W, encm_b, encs_W, encs_b, prim_W, prim_b,
                                   pris_W, pris_b, heads);
        k3b<<<320, 256, 0, stream>>>(heads, eps, Z, accd, t);
        k4<<<560, 256, 0, stream>>>(h, Z, data, macro, dec_W1, dec_b1, gru_Wih, gru_bih, gru_Whh,
                                    gru_bhh, dech1, giB, ghB, t);
        k5<<<400, 256, 0, stream>>>(dech1, dec_W2, dec_b2, dech2, giB, ghB, h);
    }
    k_epi_last<<<320, 256, 0, stream>>>(dech2, decm_W, decm_b, decs_W, decs_b, data, accd, NSTEP);
    k_final<<<1, 64, 0, stream>>>(accd, out);
}

// Round 3
// 10349.263 us; speedup vs baseline: 1.4350x; 1.4350x over previous
//
#include <hip/hip_runtime.h>
#include <math.h>

#define NA 10
#define NT 65
#define NB 128
#define XDIM 2
#define YDIM 20
#define ZDIM 64
#define HDIM 256
#define RMDIM 256
#define NSTEP 64
#define TS 8
#define HR (TS + 1)
#define LOG2PI 1.8378770664093453f

#define ENC_W1_S (348 * 256)
#define PRI_W1_S (346 * 256)
#define DEC_W1_S (430 * 256)
#define GRU_WIH_S (66 * 768)
#define GRU_WHH_S (256 * 768)
#define W2_S (256 * 256)
#define HEADW_S (256 * 64)
#define SZH (NA * NB * 256)   // 327680
#define SZZ (NA * NB * ZDIM)  // 81920

static __device__ __forceinline__ float sp(float x) {
    return fmaxf(x, 0.f) + log1pf(expf(-fabsf(x)));
}
static __device__ __forceinline__ float sigm(float x) { return 1.f / (1.f + expf(-x)); }
static __device__ __forceinline__ float relu(float x) { return fmaxf(x, 0.f); }

// ---------------- core: lane=row (64 rows), 8 cols per wave, W via scalar loads ---------------
// Xs4: 64 rows x 16 float4 (K=64 chunk), float4-slot swizzled with (tc ^ (row&15)).
__device__ __forceinline__ void chunk_fma8(float acc[8], const float4* Xs4, int m,
                                           const float* __restrict__ W, int wld, int n0u) {
#pragma unroll 4
    for (int kk4 = 0; kk4 < 16; ++kk4) {
        float4 xv = Xs4[m * 16 + (kk4 ^ (m & 15))];
        const float* w0 = W + (kk4 * 4) * wld + n0u;
        const float* w1 = w0 + wld;
        const float* w2 = w1 + wld;
        const float* w3 = w2 + wld;
#pragma unroll
        for (int j = 0; j < 8; ++j) acc[j] = fmaf(xv.x, w0[j], acc[j]);
#pragma unroll
        for (int j = 0; j < 8; ++j) acc[j] = fmaf(xv.y, w1[j], acc[j]);
#pragma unroll
        for (int j = 0; j < 8; ++j) acc[j] = fmaf(xv.z, w2[j], acc[j]);
#pragma unroll
        for (int j = 0; j < 8; ++j) acc[j] = fmaf(xv.w, w3[j], acc[j]);
    }
}

__device__ __forceinline__ void stage64(float4* Xs4, int tid, const float* __restrict__ src,
                                        int ld) {
    int tr = tid >> 4, tc = tid & 15;
#pragma unroll
    for (int p = 0; p < 4; ++p) {
        int row = tr + p * 16;
        float4 v = *(const float4*)(src + row * ld + tc * 4);
        Xs4[row * 16 + (tc ^ (row & 15))] = v;
    }
}

__device__ __forceinline__ void stage64_pad(float4* Xs4, int tid, const float* __restrict__ src,
                                            int ld, int ncols) {
    int tr = tid >> 4, tc = tid & 15;
#pragma unroll
    for (int p = 0; p < 4; ++p) {
        int row = tr + p * 16;
        float4 v = make_float4(0.f, 0.f, 0.f, 0.f);
        if (tc * 4 < ncols) v = *(const float4*)(src + row * ld + tc * 4);
        Xs4[row * 16 + (tc ^ (row & 15))] = v;
    }
}

// transpose 64x32 tile through LDS for coalesced global store. Sf aliases Xs4 (needs 2304 floats).
__device__ __forceinline__ void store_tile32(float* Sf, int tid, const float vals[8],
                                             float* __restrict__ outbase, int oldim) {
    int lane = tid & 63, wv = tid >> 6;
    __syncthreads();
#pragma unroll
    for (int j = 0; j < 8; ++j) Sf[lane * 36 + wv * 8 + j] = vals[j];
    __syncthreads();
    int r = tid >> 2, q = tid & 3;
    float4 v0 = *(float4*)(Sf + r * 36 + q * 8);
    float4 v1 = *(float4*)(Sf + r * 36 + q * 8 + 4);
    *(float4*)(outbase + r * oldim + q * 8) = v0;
    *(float4*)(outbase + r * oldim + q * 8 + 4) = v1;
}

__global__ __launch_bounds__(256) void k_init(float* __restrict__ h0, double* __restrict__ accd) {
    int i = blockIdx.x * 256 + threadIdx.x;
    ((float4*)h0)[i] = make_float4(0.f, 0.f, 0.f, 0.f);  // grid 320: exactly SZH floats
    if (i == 0) {
        accd[0] = 0.0;
        accd[1] = 0.0;
    }
}

// S1: enc1 (0..159), pri1 (160..319), gh (320..799). All K=256 over h_t.
__global__ __launch_bounds__(256) void kS1(const float* __restrict__ h,
                                           const float* __restrict__ enc_W1,
                                           const float* __restrict__ enc_b1,
                                           const float* __restrict__ pri_W1,
                                           const float* __restrict__ pri_b1,
                                           const float* __restrict__ gru_Whh,
                                           const float* __restrict__ gru_bhh,
                                           const float* __restrict__ data,
                                           const int* __restrict__ macro, float* __restrict__ ench1,
                                           float* __restrict__ prih1, float* __restrict__ ghB,
                                           int t) {
    __shared__ float4 Xs4[64 * 16];
    int tid = threadIdx.x, bid = blockIdx.x;
    int lane = tid & 63, wv = tid >> 6;
    int ep, a, b0, c0;
    const float* Wb;
    int wld;
    float* outp;
    int oldim;
    if (bid < 160) {
        ep = 0; a = bid / 16; int r = bid % 16; b0 = (r >> 3) * 64; c0 = (r & 7) * 32;
        Wb = enc_W1 + a * ENC_W1_S + 92 * 256; wld = 256; outp = ench1; oldim = 256;
    } else if (bid < 320) {
        int q = bid - 160;
        ep = 1; a = q / 16; int r = q % 16; b0 = (r >> 3) * 64; c0 = (r & 7) * 32;
        Wb = pri_W1 + a * PRI_W1_S + 90 * 256; wld = 256; outp = prih1; oldim = 256;
    } else {
        int q = bid - 320;
        ep = 2; a = q / 48; int r = q % 48; b0 = (r >= 24) ? 64 : 0; c0 = (r % 24) * 32;
        Wb = gru_Whh + a * GRU_WHH_S; wld = 768; outp = ghB; oldim = 768;
    }
    int n0u = __builtin_amdgcn_readfirstlane(c0 + wv * 8);
    const float* X = h + (a * NB + b0) * RMDIM;
    float acc[8] = {};
    for (int kb = 0; kb < 256; kb += 64) {
        stage64(Xs4, tid, X + kb, RMDIM);
        __syncthreads();
        chunk_fma8(acc, Xs4, lane, Wb + kb * wld, wld, n0u);
        __syncthreads();
    }
    float vals[8];
    int row = b0 + lane;
    if (ep == 2) {
#pragma unroll
        for (int j = 0; j < 8; ++j) vals[j] = acc[j] + gru_bhh[a * 768 + n0u + j];
    } else {
        const float* W1b = (ep == 0) ? enc_W1 + a * ENC_W1_S : pri_W1 + a * PRI_W1_S;
        const float* bb = (ep == 0) ? enc_b1 + a * HDIM : pri_b1 + a * HDIM;
        int mi = macro[(t * NB + row) * NA + a];
        const float* mrow = W1b + (ep == 0 ? 2 + mi : mi) * 256;
        float xv0 = 0.f, xv1 = 0.f;
        if (ep == 0) {
            xv0 = data[(t + 1) * (NB * YDIM) + row * YDIM + a * XDIM];
            xv1 = data[(t + 1) * (NB * YDIM) + row * YDIM + a * XDIM + 1];
        }
#pragma unroll
        for (int j = 0; j < 8; ++j) {
            float v = acc[j] + bb[n0u + j] + mrow[n0u + j];
            if (ep == 0) v += xv0 * W1b[n0u + j] + xv1 * W1b[256 + n0u + j];
            vals[j] = relu(v);
        }
    }
    store_tile32((float*)Xs4, tid, vals, outp + (a * NB + b0) * oldim + c0, oldim);
}

// S2: enc2 (0..159), pri2 (160..319). K=256.
__global__ __launch_bounds__(256) void kS2(const float* __restrict__ ench1,
                                           const float* __restrict__ prih1,
                                           const float* __restrict__ enc_W2,
                                           const float* __restrict__ enc_b2,
                                           const float* __restrict__ pri_W2,
                                           const float* __restrict__ pri_b2,
                                           float* __restrict__ ench2, float* __restrict__ prih2) {
    __shared__ float4 Xs4[64 * 16];
    int tid = threadIdx.x, bid = blockIdx.x;
    int lane = tid & 63, wv = tid >> 6;
    int isenc = bid < 160;
    int q = isenc ? bid : bid - 160;
    int a = q / 16;
    int r = q % 16;
    int b0 = (r >> 3) * 64, c0 = (r & 7) * 32;
    int n0u = __builtin_amdgcn_readfirstlane(c0 + wv * 8);
    const float* X = (isenc ? ench1 : prih1) + (a * NB + b0) * HDIM;
    const float* Wb = (isenc ? enc_W2 : pri_W2) + a * W2_S;
    const float* bb = (isenc ? enc_b2 : pri_b2) + a * HDIM;
    float acc[8] = {};
    for (int kb = 0; kb < 256; kb += 64) {
        stage64(Xs4, tid, X + kb, HDIM);
        __syncthreads();
        chunk_fma8(acc, Xs4, lane, Wb + kb * 256, 256, n0u);
        __syncthreads();
    }
    float vals[8];
#pragma unroll
    for (int j = 0; j < 8; ++j) vals[j] = relu(acc[j] + bb[n0u + j]);
    float* outp = isenc ? ench2 : prih2;
    store_tile32((float*)Xs4, tid, vals, outp + (a * NB + b0) * HDIM + c0, HDIM);
}

// S3: 4 z-heads. bid -> (a, rowgrp, head, colhalf). cols 64 per head, 32 per block.
__global__ __launch_bounds__(256) void kS3(const float* __restrict__ ench2,
                                           const float* __restrict__ prih2,
                                           const float* __restrict__ encm_W,
                                           const float* __restrict__ encm_b,
                                           const float* __restrict__ encs_W,
                                           const float* __restrict__ encs_b,
                                           const float* __restrict__ prim_W,
                                           const float* __restrict__ prim_b,
                                           const float* __restrict__ pris_W,
                                           const float* __restrict__ pris_b,
                                           float* __restrict__ heads) {
    __shared__ float4 Xs4[64 * 16];
    int tid = threadIdx.x, bid = blockIdx.x;
    int lane = tid & 63, wv = tid >> 6;
    int a = bid / 16;
    int r = bid % 16;
    int b0 = (r >> 3) * 64;
    int hc = r & 7;
    int head = hc >> 1, c0 = (hc & 1) * 32;
    const float* Wt;
    const float* Bt;
    if (head == 0) { Wt = encm_W; Bt = encm_b; }
    else if (head == 1) { Wt = encs_W; Bt = encs_b; }
    else if (head == 2) { Wt = prim_W; Bt = prim_b; }
    else { Wt = pris_W; Bt = pris_b; }
    int n0u = __builtin_amdgcn_readfirstlane(c0 + wv * 8);
    const float* X = (head < 2 ? ench2 : prih2) + (a * NB + b0) * HDIM;
    const float* Wb = Wt + a * HEADW_S;
    float acc[8] = {};
    for (int kb = 0; kb < 256; kb += 64) {
        stage64(Xs4, tid, X + kb, HDIM);
        __syncthreads();
        chunk_fma8(acc, Xs4, lane, Wb + kb * ZDIM, ZDIM, n0u);
        __syncthreads();
    }
    float vals[8];
#pragma unroll
    for (int j = 0; j < 8; ++j) vals[j] = acc[j] + Bt[a * ZDIM + n0u + j];
    store_tile32((float*)Xs4, tid, vals, heads + (a * NB + b0) * 256 + head * 64 + c0, 256);
}

// S4: z-stage (+write z_t, KL) + gi (3 gates, K=64 over z) + GRU combine -> h_{t+1}.
__global__ __launch_bounds__(256) void kS4(const float* __restrict__ heads,
                                           const float* __restrict__ eps,
                                           const float* __restrict__ data,
                                           const float* __restrict__ gru_Wih,
                                           const float* __restrict__ gru_bih,
                                           const float* __restrict__ ghB,
                                           const float* __restrict__ h_t, float* __restrict__ h_nx,
                                           float* __restrict__ z_t, double* __restrict__ accd,
                                           int t) {
    __shared__ float4 Xs4[64 * 16];
    __shared__ float red[256];
    int tid = threadIdx.x, bid = blockIdx.x;
    int lane = tid & 63, wv = tid >> 6;
    int a = bid / 16;
    int r = bid % 16;
    int b0 = (r >> 3) * 64, c0 = (r & 7) * 32;
    int n0u = __builtin_amdgcn_readfirstlane(c0 + wv * 8);
    {
        int tr = tid >> 4, tc = tid & 15;
#pragma unroll
        for (int p = 0; p < 4; ++p) {
            int rw = tr + p * 16;
            const float* hh = heads + (a * NB + b0 + rw) * 256 + tc * 4;
            float4 em = *(const float4*)hh;
            float4 es = *(const float4*)(hh + 64);
            const float* ee = eps + ((t * NA + a) * NB + b0 + rw) * ZDIM + tc * 4;
            float4 ev = *(const float4*)ee;
            float4 zv;
            zv.x = em.x + ev.x * sp(es.x);
            zv.y = em.y + ev.y * sp(es.y);
            zv.z = em.z + ev.z * sp(es.z);
            zv.w = em.w + ev.w * sp(es.w);
            Xs4[rw * 16 + (tc ^ (rw & 15))] = zv;
            if (c0 == 0) *(float4*)(z_t + (a * NB + b0 + rw) * ZDIM + tc * 4) = zv;
        }
    }
    __syncthreads();
    float acc[3][8] = {};
    const float* Wihz = gru_Wih + a * GRU_WIH_S + 2 * 768;
#pragma unroll
    for (int g = 0; g < 3; ++g) chunk_fma8(acc[g], Xs4, lane, Wihz, 768, g * 256 + n0u);
    // epilogue: x-term + bias + GRU combine
    int row = b0 + lane;
    float xv0 = data[(t + 1) * (NB * YDIM) + row * YDIM + a * XDIM];
    float xv1 = data[(t + 1) * (NB * YDIM) + row * YDIM + a * XDIM + 1];
    const float* Wih0 = gru_Wih + a * GRU_WIH_S;
    const float* bih = gru_bih + a * 768;
    const float* ghr = ghB + (a * NB + row) * 768;
    const float* hor = h_t + (a * NB + row) * 256;
    float vals[8];
#pragma unroll
    for (int j = 0; j < 8; ++j) {
        int cr = n0u + j;
        float gi0 = acc[0][j] + bih[cr] + xv0 * Wih0[cr] + xv1 * Wih0[768 + cr];
        float gi1 = acc[1][j] + bih[256 + cr] + xv0 * Wih0[256 + cr] + xv1 * Wih0[768 + 256 + cr];
        float gi2 = acc[2][j] + bih[512 + cr] + xv0 * Wih0[512 + cr] + xv1 * Wih0[768 + 512 + cr];
        float hrv = ghr[cr], hzv = ghr[256 + cr], hnv = ghr[512 + cr];
        float hov = hor[cr];
        float rr = sigm(gi0 + hrv);
        float uu = sigm(gi1 + hzv);
        float nn = tanhf(gi2 + rr * hnv);
        vals[j] = (1.f - uu) * nn + uu * hov;
    }
    store_tile32((float*)Xs4, tid, vals, h_nx + (a * NB + b0) * 256 + c0, 256);
    if (c0 == 0) {
        float part = 0.f;
        for (int qq = tid; qq < 1024; qq += 256) {
            int rw = qq >> 4, z4 = (qq & 15) * 4;
            const float* hh = heads + (a * NB + b0 + rw) * 256 + z4;
            float4 em = *(const float4*)hh;
            float4 es4 = *(const float4*)(hh + 64);
            float4 pm = *(const float4*)(hh + 128);
            float4 ps4 = *(const float4*)(hh + 192);
#pragma unroll
            for (int e = 0; e < 4; ++e) {
                float emv = (&em.x)[e], esv = sp((&es4.x)[e]);
                float pmv = (&pm.x)[e], psv = sp((&ps4.x)[e]);
                float dm = emv - pmv;
                part += 0.5f * (2.f * logf(psv) - 2.f * logf(esv) +
                                (esv * esv + dm * dm) / (psv * psv) - 1.f);
            }
        }
        red[tid] = part;
        __syncthreads();
#pragma unroll
        for (int s = 128; s > 0; s >>= 1) {
            if (tid < s) red[tid] += red[tid + s];
            __syncthreads();
        }
        if (tid == 0) atomicAdd(&accd[1], (double)red[0]);
    }
}

// Phase 2 (interleaved every TS steps): dec1 for TS steps. grid TS*160.
__global__ __launch_bounds__(256) void kDec1(const float* __restrict__ data,
                                             const int* __restrict__ macro,
                                             const float* __restrict__ z_ring,
                                             const float* __restrict__ h_ring,
                                             const float* __restrict__ dec_W1,
                                             const float* __restrict__ dec_b1,
                                             float* __restrict__ dech1s, int t0) {
    __shared__ float4 Xs4[64 * 16];
    int tid = threadIdx.x, bid = blockIdx.x;
    int lane = tid & 63, wv = tid >> 6;
    int ti = bid / 160;
    int rem = bid % 160;
    int a = rem / 16;
    int r = rem % 16;
    int b0 = (r >> 3) * 64, c0 = (r & 7) * 32;
    int t = t0 + ti;
    int n0u = __builtin_amdgcn_readfirstlane(c0 + wv * 8);
    const float* Wb = dec_W1 + a * DEC_W1_S;
    float acc[8] = {};
    // y segment (rows 0..19, padded to 64; weight rows 20..63 see zeros)
    stage64_pad(Xs4, tid, data + t * (NB * YDIM) + b0 * YDIM, YDIM, 20);
    __syncthreads();
    chunk_fma8(acc, Xs4, lane, Wb, 256, n0u);
    __syncthreads();
    // z segment (rows 110..173)
    stage64(Xs4, tid, z_ring + (size_t)(t % TS) * SZZ + (a * NB + b0) * ZDIM, ZDIM);
    __syncthreads();
    chunk_fma8(acc, Xs4, lane, Wb + 110 * 256, 256, n0u);
    __syncthreads();
    // h segment (rows 174..429)
    const float* X = h_ring + (size_t)(t % HR) * SZH + (a * NB + b0) * 256;
    for (int kb = 0; kb < 256; kb += 64) {
        stage64(Xs4, tid, X + kb, 256);
        __syncthreads();
        chunk_fma8(acc, Xs4, lane, Wb + (174 + kb) * 256, 256, n0u);
        __syncthreads();
    }
    int row = b0 + lane;
    int mi = macro[(t * NB + row) * NA + a];
    const float* mrow = Wb + (20 + mi) * 256;
    const float* bb = dec_b1 + a * HDIM;
    float vals[8];
#pragma unroll
    for (int j = 0; j < 8; ++j) vals[j] = relu(acc[j] + bb[n0u + j] + mrow[n0u + j]);
    store_tile32((float*)Xs4, tid, vals, dech1s + ((ti * NA + a) * NB + b0) * 256 + c0, 256);
}

__global__ __launch_bounds__(256) void kDec2(const float* __restrict__ dech1s,
                                             const float* __restrict__ dec_W2,
                                             const float* __restrict__ dec_b2,
                                             float* __restrict__ dech2s) {
    __shared__ float4 Xs4[64 * 16];
    int tid = threadIdx.x, bid = blockIdx.x;
    int lane = tid & 63, wv = tid >> 6;
    int ti = bid / 160;
    int rem = bid % 160;
    int a = rem / 16;
    int r = rem % 16;
    int b0 = (r >> 3) * 64, c0 = (r & 7) * 32;
    int n0u = __builtin_amdgcn_readfirstlane(c0 + wv * 8);
    const float* X = dech1s + ((ti * NA + a) * NB + b0) * 256;
    const float* Wb = dec_W2 + a * W2_S;
    float acc[8] = {};
    for (int kb = 0; kb < 256; kb += 64) {
        stage64(Xs4, tid, X + kb, 256);
        __syncthreads();
        chunk_fma8(acc, Xs4, lane, Wb + kb * 256, 256, n0u);
        __syncthreads();
    }
    const float* bb = dec_b2 + a * HDIM;
    float vals[8];
#pragma unroll
    for (int j = 0; j < 8; ++j) vals[j] = relu(acc[j] + bb[n0u + j]);
    store_tile32((float*)Xs4, tid, vals, dech2s + ((ti * NA + a) * NB + b0) * 256 + c0, 256);
}

// dec heads + recon for TS steps: one wave per (ti,a,b).
__global__ __launch_bounds__(256) void kEpi(const float* __restrict__ dech2s,
                                            const float* __restrict__ decm_W,
                                            const float* __restrict__ decm_b,
                                            const float* __restrict__ decs_W,
                                            const float* __restrict__ decs_b,
                                            const float* __restrict__ data,
                                            double* __restrict__ accd, int t0) {
    int tid = threadIdx.x;
    int widx = blockIdx.x * 4 + (tid >> 6);
    int lane = tid & 63;
    int ti = widx / 1280;
    int rem = widx - ti * 1280;
    int a = rem >> 7, b = rem & 127;
    int targ = t0 + ti + 1;
    const float4 hv = *(const float4*)&dech2s[((ti * NA + a) * NB + b) * HDIM + lane * 4];
    const float* wmb = decm_W + a * (HDIM * XDIM) + lane * 8;
    const float4 wm0 = *(const float4*)&wmb[0];
    const float4 wm1 = *(const float4*)&wmb[4];
    const float* wsb = decs_W + a * (HDIM * XDIM) + lane * 8;
    const float4 ws0 = *(const float4*)&wsb[0];
    const float4 ws1 = *(const float4*)&wsb[4];
    float m0 = hv.x * wm0.x + hv.y * wm0.z + hv.z * wm1.x + hv.w * wm1.z;
    float m1 = hv.x * wm0.y + hv.y * wm0.w + hv.z * wm1.y + hv.w * wm1.w;
    float s0 = hv.x * ws0.x + hv.y * ws0.z + hv.z * ws1.x + hv.w * ws1.z;
    float s1 = hv.x * ws0.y + hv.y * ws0.w + hv.z * ws1.y + hv.w * ws1.w;
#pragma unroll
    for (int off = 32; off > 0; off >>= 1) {
        m0 += __shfl_down(m0, off, 64);
        m1 += __shfl_down(m1, off, 64);
        s0 += __shfl_down(s0, off, 64);
        s1 += __shfl_down(s1, off, 64);
    }
    if (lane == 0) {
        float dm0 = m0 + decm_b[a * 2 + 0];
        float dm1 = m1 + decm_b[a * 2 + 1];
        float ds0 = sp(s0 + decs_b[a * 2 + 0]);
        float ds1 = sp(s1 + decs_b[a * 2 + 1]);
        float x0 = data[targ * (NB * YDIM) + b * YDIM + a * XDIM + 0];
        float x1 = data[targ * (NB * YDIM) + b * YDIM + a * XDIM + 1];
        float r0 = (x0 - dm0) / ds0, r1 = (x1 - dm1) / ds1;
        float tt = 0.5f * r0 * r0 + logf(ds0) + 0.5f * LOG2PI + 0.5f * r1 * r1 + logf(ds1) +
                   0.5f * LOG2PI;
        atomicAdd(&accd[0], (double)tt);
    }
}

__global__ void k_final(const double* __restrict__ accd, float* __restrict__ out) {
    if (threadIdx.x == 0) {
        out[0] = (float)accd[0];
        out[1] = (float)accd[1];
    }
}

extern "C" void kernel_launch(void* const* d_in, const int* in_sizes, int n_in, void* d_out,
                              int out_size, void* d_ws, size_t ws_size, hipStream_t stream) {
    const float* data = (const float*)d_in[0];
    const int* macro = (const int*)d_in[1];
    const float* eps = (const float*)d_in[2];
    const float* enc_W1 = (const float*)d_in[3];
    const float* enc_b1 = (const float*)d_in[4];
    const float* enc_W2 = (const float*)d_in[5];
    const float* enc_b2 = (const float*)d_in[6];
    const float* encm_W = (const float*)d_in[7];
    const float* encm_b = (const float*)d_in[8];
    const float* encs_W = (const float*)d_in[9];
    const float* encs_b = (const float*)d_in[10];
    const float* pri_W1 = (const float*)d_in[11];
    const float* pri_b1 = (const float*)d_in[12];
    const float* pri_W2 = (const float*)d_in[13];
    const float* pri_b2 = (const float*)d_in[14];
    const float* prim_W = (const float*)d_in[15];
    const float* prim_b = (const float*)d_in[16];
    const float* pris_W = (const float*)d_in[17];
    const float* pris_b = (const float*)d_in[18];
    const float* dec_W1 = (const float*)d_in[19];
    const float* dec_b1 = (const float*)d_in[20];
    const float* dec_W2 = (const float*)d_in[21];
    const float* dec_b2 = (const float*)d_in[22];
    const float* decm_W = (const float*)d_in[23];
    const float* decm_b = (const float*)d_in[24];
    const float* decs_W = (const float*)d_in[25];
    const float* decs_b = (const float*)d_in[26];
    const float* gru_Wih = (const float*)d_in[27];
    const float* gru_bih = (const float*)d_in[28];
    const float* gru_Whh = (const float*)d_in[29];
    const float* gru_bhh = (const float*)d_in[30];

    // workspace layout (~46 MB)
    double* accd = (double*)d_ws;
    float* base = (float*)((char*)d_ws + 256);
    float* h_ring = base;                           // HR * SZH  (9 slots)
    float* z_ring = h_ring + (size_t)HR * SZH;      // TS * SZZ  (8 slots)
    float* ench1 = z_ring + (size_t)TS * SZZ;
    float* prih1 = ench1 + SZH;
    float* ench2 = prih1 + SZH;
    float* prih2 = ench2 + SZH;
    float* heads = prih2 + SZH;
    float* ghB = heads + SZH;                       // NA*NB*768
    float* dech1s = ghB + NA * NB * 768;            // TS * SZH
    float* dech2s = dech1s + (size_t)TS * SZH;      // TS * SZH
    float* out = (float*)d_out;

    k_init<<<320, 256, 0, stream>>>(h_ring, accd);  // h slot 0 = h_0 = zeros
    for (int t = 0; t < NSTEP; ++t) {
        float* h_t = h_ring + (size_t)(t % HR) * SZH;
        float* h_nx = h_ring + (size_t)((t + 1) % HR) * SZH;
        float* z_t = z_ring + (size_t)(t % TS) * SZZ;
        kS1<<<800, 256, 0, stream>>>(h_t, enc_W1, enc_b1, pri_W1, pri_b1, gru_Whh, gru_bhh, data,
                                     macro, ench1, prih1, ghB, t);
        kS2<<<320, 256, 0, stream>>>(ench1, prih1, enc_W2, enc_b2, pri_W2, pri_b2, ench2, prih2);
        kS3<<<160, 256, 0, stream>>>(ench2, prih2, encm_W, encm_b, encs_W, encs_b, prim_W, prim_b,
                                     pris_W, pris_b, heads);
        kS4<<<160, 256, 0, stream>>>(heads, eps, data, gru_Wih, gru_bih, ghB, h_t, h_nx, z_t, accd,
                                     t);
        if ((t % TS) == TS - 1) {
            int t0 = t - TS + 1;
            kDec1<<<TS * 160, 256, 0, stream>>>(data, macro, z_ring, h_ring, dec_W1, dec_b1,
                                                dech1s, t0);
            kDec2<<<TS * 160, 256, 0, stream>>>(dech1s, dec_W2, dec_b2, dech2s);
            kEpi<<<TS * 320, 256, 0, stream>>>(dech2s, decm_W, decm_b, decs_W, decs_b, data, accd,
                                               t0);
        }
    }
    k_final<<<1, 64, 0, stream>>>(accd, out);
}